// Round 13
// baseline (1492.116 us; speedup 1.0000x reference)
//
#include <hip/hip_runtime.h>

// ---------------------------------------------------------------------------
// MultiHeadAttention (full-width per-head projections), MI355X gfx950.
// Round 13: launch restructure only (all GEMM K-loops = replay-verified
// gemm_core64 verbatim).
//  - k_su_b (73us, LDS-capped) split: k_su_y = k_w+sh @36KB LDS (4+ blk/CU),
//    k_su_x = MT(0,1)+NT(0,1) @64KB.
//  - MT(h+2)/NT(h+2) production distributed into SMG1(h) (absorbed in the
//    softmax blocks' early-finish slack; one-launch producer->consumer gap).
//  - All buffers persistent (no overlays): ws ~306 MB <= proven 326.6 MB;
//    per-launch working sets < 256 MB L3.
// Math unchanged:
//   scores = softmax_t( 8*( x M_h x^T + w_t ) ),  M_h = Wq_h Wk_h^T
//   out    = sum_h P_h Z_h + bp,  Z_h = x N_h + bv_h Wp_h,  N_h = Wv_h Wp_h
// ---------------------------------------------------------------------------

typedef __attribute__((ext_vector_type(8))) short bf16x8;
typedef __attribute__((ext_vector_type(4))) float fx4;

#define NB 8
#define NS 1024
#define ND 768
#define NH 12

__device__ __forceinline__ unsigned short f2bf(float x) {
    unsigned int u = __float_as_uint(x);
    u += 0x7fffu + ((u >> 16) & 1u);   // round-to-nearest-even bf16
    return (unsigned short)(u >> 16);
}
__device__ __forceinline__ float bf2f(unsigned short h) {
    return __uint_as_float(((unsigned int)h) << 16);
}

// async global->LDS, 16B per lane; LDS base must be wave-uniform.
__device__ __forceinline__ void gll16(const void* g, void* l) {
    __builtin_amdgcn_global_load_lds(
        (const __attribute__((address_space(1))) void*)g,
        (__attribute__((address_space(3))) void*)l, 16, 0, 0);
}

// ---------------- elementwise body -------------------------------------------
__device__ __forceinline__ void split_body(const float* __restrict__ in,
                                           unsigned short* __restrict__ hi,
                                           unsigned short* __restrict__ lo, int i) {
    float4 v = ((const float4*)in)[i];
    ushort4 h, l;
    h.x = f2bf(v.x); l.x = f2bf(v.x - bf2f(h.x));
    h.y = f2bf(v.y); l.y = f2bf(v.y - bf2f(h.y));
    h.z = f2bf(v.z); l.z = f2bf(v.z - bf2f(h.z));
    h.w = f2bf(v.w); l.w = f2bf(v.w - bf2f(h.w));
    ((ushort4*)hi)[i] = h;
    ((ushort4*)lo)[i] = l;
}

// ---------------------------------------------------------------------------
// gemm_core64 — replay-verified (R9..R12): 128x128 tile, BK=64, 4 waves,
// single-buffer, per K-tile: sync -> stage (global_load_lds) -> sync -> ds+MFMA.
// LDS [128][64] bf16 tiles (16KB each). Swizzle pc = c_log ^ (row&7);
// staging source chunk (lane&7)^(lane>>3), linear LDS dest -> 0 conflicts.
// C/D layout (HW-verified): col = lane&15, row = (lane>>4)*4 + reg.
// ---------------------------------------------------------------------------
template<int NTERMS, class Epi>
__device__ __forceinline__ void gemm_core64(
    char* __restrict__ smem,
    const unsigned short* __restrict__ Ah, const unsigned short* __restrict__ Al, int lda,
    const unsigned short* __restrict__ Bh, const unsigned short* __restrict__ Bl, int ldb,
    int K, Epi epi)
{
    constexpr int TILE = 16384;              // bytes per [128][64] bf16 tile

    const int t = threadIdx.x;
    const int lane = t & 63;
    const int w = t >> 6;
    const int wm = (w >> 1) << 6;
    const int wn = (w & 1) << 6;
    const int lr = lane & 15;
    const int lg = lane >> 4;

    const int l3 = lane >> 3;
    const int cs = (lane & 7) ^ l3;
    const int ldsw = w << 12;                // wave-uniform LDS byte offset

    const long gsA = (long)(w * 32 + l3) * lda * 2 + cs * 16;
    const long gsB = (long)(w * 32 + l3) * ldb * 2 + cs * 16;
    const long giA = (long)lda * 16;         // +8 rows, in bytes
    const long giB = (long)ldb * 16;

    const char* pAh = (const char*)Ah;
    const char* pBh = (const char*)Bh;
    const char* pAl = (const char*)Al;
    const char* pBl = (const char*)Bl;
    char* smA  = smem;
    char* smB  = smem + TILE;
    char* smA2 = smem + ((NTERMS == 3) ? 2 * TILE : 0);
    char* smB2 = smem + ((NTERMS == 3) ? 3 * TILE : TILE);

    int rowA[4], rowB[4];
    #pragma unroll
    for (int i = 0; i < 4; i++) {
        rowA[i] = (wm + (i << 4) + lr) << 6;   // ushort index of row base
        rowB[i] = (wn + (i << 4) + lr) << 6;
    }
    const int lr7 = lr & 7;

    fx4 acc[4][4] = {};

    for (int k0 = 0; k0 < K; k0 += 64) {
        const long kb2 = (long)k0 * 2;
        __syncthreads();
        #pragma unroll
        for (int ii = 0; ii < 4; ii++) {
            const int lo = ldsw + (ii << 10);
            gll16(pAh + gsA + ii * giA + kb2, smA + lo);
            gll16(pBh + gsB + ii * giB + kb2, smB + lo);
            if constexpr (NTERMS == 3) {
                gll16(pAl + gsA + ii * giA + kb2, smA2 + lo);
                gll16(pBl + gsB + ii * giB + kb2, smB2 + lo);
            }
        }
        __syncthreads();

        #pragma unroll
        for (int kk = 0; kk < 2; kk++) {
            const int pc = (((kk << 2) + lg) ^ lr7) << 3;   // ushort offset
            bf16x8 fa[4], fb[4], fa2[4], fb2[4];
            #pragma unroll
            for (int i = 0; i < 4; i++) {
                fa[i] = *(const bf16x8*)((const unsigned short*)smA + rowA[i] + pc);
                fb[i] = *(const bf16x8*)((const unsigned short*)smB + rowB[i] + pc);
            }
            if constexpr (NTERMS == 3) {
                #pragma unroll
                for (int i = 0; i < 4; i++) {
                    fa2[i] = *(const bf16x8*)((const unsigned short*)smA2 + rowA[i] + pc);
                    fb2[i] = *(const bf16x8*)((const unsigned short*)smB2 + rowB[i] + pc);
                }
            }
            #pragma unroll
            for (int i = 0; i < 4; i++)
                #pragma unroll
                for (int j = 0; j < 4; j++) {
                    acc[i][j] = __builtin_amdgcn_mfma_f32_16x16x32_bf16(fa[i], fb[j], acc[i][j], 0, 0, 0);
                    if constexpr (NTERMS == 3) {
                        acc[i][j] = __builtin_amdgcn_mfma_f32_16x16x32_bf16(fa[i], fb2[j], acc[i][j], 0, 0, 0);
                        acc[i][j] = __builtin_amdgcn_mfma_f32_16x16x32_bf16(fa2[i], fb[j], acc[i][j], 0, 0, 0);
                    }
                }
        }
    }

    #pragma unroll
    for (int i = 0; i < 4; i++)
        #pragma unroll
        for (int j = 0; j < 4; j++)
            #pragma unroll
            for (int r = 0; r < 4; r++)
                epi(wm + (i << 4) + (lg << 2) + r, wn + (j << 4) + lr, acc[i][j][r]);
}

// ---------------- softmax body (wave per row) --------------------------------
__device__ __forceinline__ void softmax_row_core(const float* __restrict__ rp,
                                                 unsigned short* __restrict__ drow,
                                                 int lane) {
    const float4* src = (const float4*)rp + (lane << 2);
    float v[16];
    #pragma unroll
    for (int i = 0; i < 4; i++) {
        float4 a = src[i];
        v[i * 4 + 0] = a.x; v[i * 4 + 1] = a.y; v[i * 4 + 2] = a.z; v[i * 4 + 3] = a.w;
    }
    float m = v[0];
    #pragma unroll
    for (int i = 1; i < 16; i++) m = fmaxf(m, v[i]);
    #pragma unroll
    for (int o = 32; o > 0; o >>= 1) m = fmaxf(m, __shfl_xor(m, o));
    float s = 0.f, p[16];
    #pragma unroll
    for (int i = 0; i < 16; i++) { p[i] = __expf((v[i] - m) * 8.0f); s += p[i]; }
    #pragma unroll
    for (int o = 32; o > 0; o >>= 1) s += __shfl_xor(s, o);
    float inv = 1.0f / s;
    unsigned int wrd[8];
    #pragma unroll
    for (int i = 0; i < 8; i++) {
        unsigned int u0 = f2bf(p[2 * i] * inv);
        unsigned int u1 = f2bf(p[2 * i + 1] * inv);
        wrd[i] = u0 | (u1 << 16);
    }
    uint4* dst = (uint4*)(drow + (lane << 4));
    dst[0] = make_uint4(wrd[0], wrd[1], wrd[2], wrd[3]);
    dst[1] = make_uint4(wrd[4], wrd[5], wrd[6], wrd[7]);
}

// ------------------------- merged setup launch A (R12 verbatim) --------------
// [0,6144) x split | [6144,13056) Wq split | [13056,19968) Wk split |
// [19968,22272) rk | [22272,29184) Wv cast | [29184,30912) Wp transpose.
__global__ void k_su_a(
    const float* __restrict__ x, unsigned short* __restrict__ xh, unsigned short* __restrict__ xl,
    const float* __restrict__ Wq, unsigned short* __restrict__ Wqh, unsigned short* __restrict__ Wql,
    const float* __restrict__ Wk, unsigned short* __restrict__ Wkh, unsigned short* __restrict__ Wkl,
    const float* __restrict__ bq, float* __restrict__ rk,
    const float* __restrict__ Wv, unsigned short* __restrict__ Wvb,
    const float* __restrict__ Wp, unsigned short* __restrict__ WpT)
{
    __shared__ float tile[64][65];
    const int bx = blockIdx.x;
    if (bx < 6144) {
        split_body(x, xh, xl, bx * 256 + threadIdx.x);
    } else if (bx < 13056) {
        split_body(Wq, Wqh, Wql, (bx - 6144) * 256 + threadIdx.x);
    } else if (bx < 19968) {
        split_body(Wk, Wkh, Wkl, (bx - 13056) * 256 + threadIdx.x);
    } else if (bx < 22272) {
        const int idx = bx - 19968;            // [0,2304)
        const int h = idx / 192;
        const int d = (idx % 192) * 4 + ((int)threadIdx.x >> 6);
        const int lane = threadIdx.x & 63;
        const float4* row = (const float4*)(Wk + ((long)h * ND + d) * ND);
        const float4* bv4 = (const float4*)(bq + h * ND);
        float acc = 0.f;
        #pragma unroll
        for (int i = 0; i < 3; i++) {
            float4 a = row[lane + (i << 6)];
            float4 b = bv4[lane + (i << 6)];
            acc += a.x * b.x + a.y * b.y + a.z * b.z + a.w * b.w;
        }
        #pragma unroll
        for (int o = 32; o > 0; o >>= 1) acc += __shfl_xor(acc, o);
        if (lane == 0) rk[h * ND + d] = acc;
    } else if (bx < 29184) {
        int i = (bx - 22272) * 256 + threadIdx.x;
        float4 v = ((const float4*)Wv)[i];
        ushort4 h;
        h.x = f2bf(v.x); h.y = f2bf(v.y); h.z = f2bf(v.z); h.w = f2bf(v.w);
        ((ushort4*)Wvb)[i] = h;
    } else {
        const int idx = bx - 29184;            // [0,1728)
        const int c0 = (idx % 12) * 64;
        const int r0 = ((idx / 12) % 12) * 64;
        const long zo = (long)(idx / 144) * (ND * ND);
        const float* in = Wp + zo;
        unsigned short* oh = WpT + zo;
        const int tc = threadIdx.x & 63, t4 = threadIdx.x >> 6;
        #pragma unroll
        for (int i = 0; i < 16; i++) {
            int r = (i << 2) + t4;
            tile[r][tc] = in[(long)(r0 + r) * ND + c0 + tc];
        }
        __syncthreads();
        #pragma unroll
        for (int i = 0; i < 16; i++) {
            int c = (i << 2) + t4;
            oh[(long)(c0 + c) * ND + r0 + tc] = f2bf(tile[tc][c]);
        }
    }
}

// ------------------------- setup Y: k_w (2048) + sh (2304), 36KB LDS ---------
__global__ __launch_bounds__(256) void k_su_y(
    const float* __restrict__ x, const float* __restrict__ rk, float* __restrict__ w_all,
    const unsigned short* __restrict__ WpT, const float* __restrict__ bv,
    float* __restrict__ s_all)
{
    __shared__ float srk[NH * ND];   // 36KB
    const int bx = blockIdx.x;
    if (bx < 2048) {
        for (int i = threadIdx.x; i < NH * ND; i += 256) srk[i] = rk[i];
        __syncthreads();
        const int row = bx * 4 + ((int)threadIdx.x >> 6);
        const int lane = threadIdx.x & 63;
        const float4* xr = (const float4*)(x + (long)row * ND);
        float4 xa[3];
        #pragma unroll
        for (int i = 0; i < 3; i++) xa[i] = xr[lane + (i << 6)];
        for (int h = 0; h < NH; h++) {
            const float* r = srk + h * ND;
            float acc = 0.f;
            #pragma unroll
            for (int i = 0; i < 3; i++) {
                int e = (lane + (i << 6)) << 2;
                acc += xa[i].x * r[e] + xa[i].y * r[e + 1]
                     + xa[i].z * r[e + 2] + xa[i].w * r[e + 3];
            }
            #pragma unroll
            for (int o = 32; o > 0; o >>= 1) acc += __shfl_xor(acc, o);
            if (lane == 0) w_all[h * (NB * NS) + row] = acc;
        }
    } else {
        const int idx = bx - 2048;             // [0,2304)
        const int h = idx / 192;
        const int j = (idx % 192) * 4 + ((int)threadIdx.x >> 6);
        const int lane = threadIdx.x & 63;
        const ushort4* row = (const ushort4*)(WpT + ((long)h * ND + j) * ND);
        const float* bvh = bv + h * ND;
        float acc = 0.f;
        #pragma unroll
        for (int i = 0; i < 3; i++) {
            int c = lane + (i << 6);
            ushort4 u = row[c];
            int e = c << 2;
            acc += bf2f(u.x) * bvh[e] + bf2f(u.y) * bvh[e + 1]
                 + bf2f(u.z) * bvh[e + 2] + bf2f(u.w) * bvh[e + 3];
        }
        #pragma unroll
        for (int o = 32; o > 0; o >>= 1) acc += __shfl_xor(acc, o);
        if (lane == 0) s_all[h * ND + j] = acc;
    }
}

// ------------- setup X: MT(0),MT(1),NT(0),NT(1) — 144 blocks, 64KB ----------
__global__ __launch_bounds__(256, 2) void k_su_x(
    const unsigned short* __restrict__ Wkh, const unsigned short* __restrict__ Wkl,
    const unsigned short* __restrict__ Wqh, const unsigned short* __restrict__ Wql,
    unsigned short* __restrict__ MTh, unsigned short* __restrict__ MTl,
    const unsigned short* __restrict__ WpT, const unsigned short* __restrict__ Wvb,
    unsigned short* __restrict__ NTo)
{
    __shared__ __align__(16) char smem[65536];
    const int bx = blockIdx.x;
    const int part = bx / 36, t = bx % 36;
    const int n0 = (t % 6) << 7;
    const int m0 = (t / 6) << 7;
    if (part < 2) {
        const long hw = (long)part * (ND * ND);
        unsigned short* oh = MTh + hw + (long)m0 * ND + n0;
        unsigned short* ol = MTl + hw + (long)m0 * ND + n0;
        gemm_core64<3>(smem, Wkh + hw + (long)m0 * ND, Wkl + hw + (long)m0 * ND, ND,
                       Wqh + hw + (long)n0 * ND, Wql + hw + (long)n0 * ND, ND, ND,
                       [=](int r, int c, float v) {
                           unsigned short hh = f2bf(v);
                           oh[r * ND + c] = hh;
                           ol[r * ND + c] = f2bf(v - bf2f(hh));
                       });
    } else {
        const long hw = (long)(part - 2) * (ND * ND);
        unsigned short* o = NTo + hw + (long)m0 * ND + n0;
        gemm_core64<1>(smem, WpT + hw + (long)m0 * ND, nullptr, ND,
                       Wvb + hw + (long)n0 * ND, nullptr, ND, ND,
                       [=](int r, int c, float v) { o[r * ND + c] = f2bf(v); });
    }
}

// ------------------------- per-head kernels ----------------------------------

// G = x * M_h (split out), head-0 bootstrap. flat grid 384 (verbatim).
__global__ __launch_bounds__(256, 2) void k_G0(
    const unsigned short* __restrict__ xh, const unsigned short* __restrict__ xl,
    const unsigned short* __restrict__ MTh, const unsigned short* __restrict__ MTl,
    unsigned short* __restrict__ Gh, unsigned short* __restrict__ Gl)
{
    __shared__ __align__(16) char smem[65536];
    const int bx = blockIdx.x;
    const int xcd = bx & 7, idx = bx >> 3;
    const int m0 = (xcd * 8 + idx / 6) << 7;
    const int n0 = (idx % 6) << 7;
    unsigned short* oh = Gh + (long)m0 * ND + n0;
    unsigned short* ol = Gl + (long)m0 * ND + n0;
    gemm_core64<3>(smem, xh + (long)m0 * ND, xl + (long)m0 * ND, ND,
                   MTh + (long)n0 * ND, MTl + (long)n0 * ND, ND, ND,
                   [=](int r, int c, float v) {
                       unsigned short hh = f2bf(v);
                       oh[(long)r * ND + c] = hh;
                       ol[(long)r * ND + c] = f2bf(v - bf2f(hh));
                   });
}

// bootstrap: scores(0)+Z(0) (verbatim). grid 896.
__global__ __launch_bounds__(256, 2) void k_SZ(
    const unsigned short* __restrict__ Gh, const unsigned short* __restrict__ Gl,
    const unsigned short* __restrict__ xh, const unsigned short* __restrict__ xl,
    const float* __restrict__ wv, float* __restrict__ Sc,
    const unsigned short* __restrict__ NTh, const float* __restrict__ sh,
    unsigned short* __restrict__ ZT)
{
    __shared__ __align__(16) char smem[65536];
    const int bx = blockIdx.x;
    if (bx < 512) {
        const int bl = bx & 7, idx = bx >> 3;
        const int m0 = (idx >> 3) << 7;
        const int n0 = (idx & 7) << 7;
        const long ao = ((long)bl * NS + m0) * ND;
        const long bo = ((long)bl * NS + n0) * ND;
        const float* ww = wv + bl * NS + n0;
        float* out = Sc + ((long)bl * NS + m0) * NS + n0;
        gemm_core64<3>(smem, Gh + ao, Gl + ao, ND, xh + bo, xl + bo, ND, ND,
                       [=](int r, int c, float v) { out[(long)r * NS + c] = v + ww[c]; });
    } else {
        const int g = bx - 512;
        const int xcd = g & 7, idx = g >> 3;
        const int m0 = (xcd * 8 + idx / 6) << 7;
        const int n0 = (idx % 6) << 7;
        const int bl = m0 >> 10;
        const int s0 = m0 & (NS - 1);
        unsigned short* zt = ZT + (long)bl * (ND * NS);
        gemm_core64<1>(smem, xh + (long)m0 * ND, nullptr, ND,
                       NTh + (long)n0 * ND, nullptr, ND, ND,
                       [=](int r, int c, float v) {
                           zt[(long)(n0 + c) * NS + s0 + r] = f2bf(v + sh[n0 + c]);
                       });
    }
}

// blocks [0,2048): softmax Sc row -> packed Pp; [2048,2432): G(h+1);
// [2432,2468): MT(h+2) production; [2468,2504): NT(h+2) production.
__global__ __launch_bounds__(256, 2) void k_SMG1(
    const float* __restrict__ Sc, unsigned short* __restrict__ Pp,
    const unsigned short* __restrict__ xh, const unsigned short* __restrict__ xl,
    const unsigned short* __restrict__ MTgh, const unsigned short* __restrict__ MTgl,
    unsigned short* __restrict__ Gh, unsigned short* __restrict__ Gl,
    const unsigned short* __restrict__ Wkh_p, const unsigned short* __restrict__ Wkl_p,
    const unsigned short* __restrict__ Wqh_p, const unsigned short* __restrict__ Wql_p,
    unsigned short* __restrict__ MTph, unsigned short* __restrict__ MTpl,
    const unsigned short* __restrict__ WpT_p, const unsigned short* __restrict__ Wvb_p,
    unsigned short* __restrict__ NTp)
{
    __shared__ __align__(16) char smem[65536];
    const int bx = blockIdx.x;
    if (bx < 2048) {
        int row = bx * 4 + ((int)threadIdx.x >> 6);
        int lane = threadIdx.x & 63;
        softmax_row_core(Sc + (long)row * NS, Pp + (long)row * NS, lane);
    } else if (bx < 2432) {
        const int g = bx - 2048;
        const int xcd = g & 7, idx = g >> 3;
        const int m0 = (xcd * 8 + idx / 6) << 7;
        const int n0 = (idx % 6) << 7;
        unsigned short* oh = Gh + (long)m0 * ND + n0;
        unsigned short* ol = Gl + (long)m0 * ND + n0;
        gemm_core64<3>(smem, xh + (long)m0 * ND, xl + (long)m0 * ND, ND,
                       MTgh + (long)n0 * ND, MTgl + (long)n0 * ND, ND, ND,
                       [=](int r, int c, float v) {
                           unsigned short hh = f2bf(v);
                           oh[(long)r * ND + c] = hh;
                           ol[(long)r * ND + c] = f2bf(v - bf2f(hh));
                       });
    } else if (bx < 2468) {
        const int t = bx - 2432;
        const int n0 = (t % 6) << 7;
        const int m0 = (t / 6) << 7;
        unsigned short* oh = MTph + (long)m0 * ND + n0;
        unsigned short* ol = MTpl + (long)m0 * ND + n0;
        gemm_core64<3>(smem, Wkh_p + (long)m0 * ND, Wkl_p + (long)m0 * ND, ND,
                       Wqh_p + (long)n0 * ND, Wql_p + (long)n0 * ND, ND, ND,
                       [=](int r, int c, float v) {
                           unsigned short hh = f2bf(v);
                           oh[r * ND + c] = hh;
                           ol[r * ND + c] = f2bf(v - bf2f(hh));
                       });
    } else {
        const int t = bx - 2468;
        const int n0 = (t % 6) << 7;
        const int m0 = (t / 6) << 7;
        unsigned short* o = NTp + (long)m0 * ND + n0;
        gemm_core64<1>(smem, WpT_p + (long)m0 * ND, nullptr, ND,
                       Wvb_p + (long)n0 * ND, nullptr, ND, ND,
                       [=](int r, int c, float v) { o[r * ND + c] = f2bf(v); });
    }
}

// blocks [0,384): PV(h) = Pp . ZTr -> d_out (write/acc);
// [384,896): scores(h+1) -> Sc; [896,1280): Z(h+1) -> ZTw. (verbatim)
template<int MODE>   // 0: first head (write + bias), 1: accumulate
__global__ __launch_bounds__(256, 2) void k_PVSZ1(
    const unsigned short* __restrict__ Pp, const unsigned short* __restrict__ ZTr,
    const float* __restrict__ bp, float* __restrict__ outp,
    const unsigned short* __restrict__ Gh, const unsigned short* __restrict__ Gl,
    const unsigned short* __restrict__ xh, const unsigned short* __restrict__ xl,
    const float* __restrict__ wv, float* __restrict__ Sc,
    const unsigned short* __restrict__ NTh, const float* __restrict__ sh,
    unsigned short* __restrict__ ZTw)
{
    __shared__ __align__(16) char smem[65536];
    const int bx = blockIdx.x;
    if (bx < 384) {
        const int bl = bx & 7, idx = bx >> 3;
        const int m0 = (idx / 6) << 7;
        const int n0 = (idx % 6) << 7;
        const unsigned short* A = Pp + ((long)bl * NS + m0) * NS;
        const unsigned short* B = ZTr + (long)bl * (ND * NS) + (long)n0 * NS;
        float* o = outp + ((long)bl * NS + m0) * ND + n0;
        const float* bi = bp + n0;
        gemm_core64<1>(smem, A, nullptr, NS, B, nullptr, NS, NS,
                       [=](int r, int c, float v) {
                           float* d = o + (long)r * ND + c;
                           if constexpr (MODE == 0) *d = v + bi[c];
                           else *d += v;
                       });
    } else if (bx < 896) {
        const int b2 = bx - 384;
        const int bl = b2 & 7, idx = b2 >> 3;
        const int m0 = (idx >> 3) << 7;
        const int n0 = (idx & 7) << 7;
        const long ao = ((long)bl * NS + m0) * ND;
        const long bo = ((long)bl * NS + n0) * ND;
        const float* ww = wv + bl * NS + n0;
        float* out = Sc + ((long)bl * NS + m0) * NS + n0;
        gemm_core64<3>(smem, Gh + ao, Gl + ao, ND, xh + bo, xl + bo, ND, ND,
                       [=](int r, int c, float v) { out[(long)r * NS + c] = v + ww[c]; });
    } else {
        const int g = bx - 896;
        const int xcd = g & 7, idx = g >> 3;
        const int m0 = (xcd * 8 + idx / 6) << 7;
        const int n0 = (idx % 6) << 7;
        const int bl = m0 >> 10;
        const int s0 = m0 & (NS - 1);
        unsigned short* zt = ZTw + (long)bl * (ND * NS);
        gemm_core64<1>(smem, xh + (long)m0 * ND, nullptr, ND,
                       NTh + (long)n0 * ND, nullptr, ND, ND,
                       [=](int r, int c, float v) {
                           zt[(long)(n0 + c) * NS + s0 + r] = f2bf(v + sh[n0 + c]);
                       });
    }
}

// ---------------------------------------------------------------------------

extern "C" void kernel_launch(void* const* d_in, const int* in_sizes, int n_in,
                              void* d_out, int out_size, void* d_ws, size_t ws_size,
                              hipStream_t stream) {
    (void)in_sizes; (void)n_in; (void)out_size; (void)ws_size;
    const float* x  = (const float*)d_in[0];
    const float* Wq = (const float*)d_in[1];
    const float* bq = (const float*)d_in[2];
    const float* Wk = (const float*)d_in[3];
    const float* bk = (const float*)d_in[4];  (void)bk;  // cancels in softmax
    const float* Wv = (const float*)d_in[5];
    const float* bv = (const float*)d_in[6];
    const float* Wp = (const float*)d_in[7];
    const float* bp = (const float*)d_in[8];

    const size_t nx  = (size_t)NB * NS * ND;   // 6,291,456
    const size_t nw  = (size_t)NH * ND * ND;   // 7,077,888
    const size_t nwh = (size_t)ND * ND;
    const size_t PPE = (size_t)NB * NS * NS;   // 8,388,608
    const size_t ZTE = (size_t)NB * NS * ND;

    char* p = (char*)d_ws;
    auto alloc = [&](size_t bytes) -> void* {
        void* r = (void*)p;
        p += (bytes + 255) & ~(size_t)255;
        return r;
    };
    // all persistent (~306 MB <= proven 326.6 MB)
    unsigned short* xh   = (unsigned short*)alloc(nx * 2);
    unsigned short* xl   = (unsigned short*)alloc(nx * 2);
    unsigned short* MTh  = (unsigned short*)alloc(nw * 2);
    unsigned short* MTl  = (unsigned short*)alloc(nw * 2);
    unsigned short* NTb  = (unsigned short*)alloc(nw * 2);
    float*          rk   = (float*)alloc((size_t)NH * ND * 4);
    float*          s_all= (float*)alloc((size_t)NH * ND * 4);
    float*          w_all= (float*)alloc((size_t)NH * NB * NS * 4);
    unsigned short* Wqh  = (unsigned short*)alloc(nw * 2);
    unsigned short* Wql  = (unsigned short*)alloc(nw * 2);
    unsigned short* Wkh  = (unsigned short*)alloc(nw * 2);
    unsigned short* Wkl  = (unsigned short*)alloc(nw * 2);
    unsigned short* Wvb  = (unsigned short*)alloc(nw * 2);
    unsigned short* WpT  = (unsigned short*)alloc(nw * 2);
    float*          Sc   = (float*)alloc(PPE * 4);
    unsigned short* Gh   = (unsigned short*)alloc(nx * 2);
    unsigned short* Gl   = (unsigned short*)alloc(nx * 2);
    unsigned short* Pp   = (unsigned short*)alloc(PPE * 2);
    unsigned short* ZT   = (unsigned short*)alloc(2 * ZTE * 2);

    // ---------------- setup (3 launches) ----------------
    k_su_a<<<30912, 256, 0, stream>>>(x, xh, xl, Wq, Wqh, Wql, Wk, Wkh, Wkl,
                                      bq, rk, Wv, Wvb, Wp, WpT);
    k_su_y<<<4352, 256, 0, stream>>>(x, rk, w_all, WpT, bv, s_all);
    k_su_x<<<144, 256, 0, stream>>>(Wkh, Wkl, Wqh, Wql, MTh, MTl, WpT, Wvb, NTb);

    // ---------------- per-head pipeline (2 launches/head) ----------------
    k_G0<<<384, 256, 0, stream>>>(xh, xl, MTh, MTl, Gh, Gl);
    k_SZ<<<896, 256, 0, stream>>>(Gh, Gl, xh, xl, w_all, Sc, NTb, s_all, ZT);
    for (int h = 0; h < NH; h++) {
        const int hn = h + 1;
        const bool hasG = hn < NH;
        const int hs = hasG ? hn : 0;
        const int hp = h + 2;
        const bool hasP = hp < NH;
        const int hpp = hasP ? hp : 0;
        const int gridS = hasP ? 2504 : (hasG ? 2432 : 2048);
        k_SMG1<<<gridS, 256, 0, stream>>>(
            Sc, Pp, xh, xl,
            MTh + (long)hs * nwh, MTl + (long)hs * nwh, Gh, Gl,
            Wkh + (long)hpp * nwh, Wkl + (long)hpp * nwh,
            Wqh + (long)hpp * nwh, Wql + (long)hpp * nwh,
            MTh + (long)hpp * nwh, MTl + (long)hpp * nwh,
            WpT + (long)hpp * nwh, Wvb + (long)hpp * nwh,
            NTb + (long)hpp * nwh);
        unsigned short* ZTr = ZT + (size_t)(h & 1) * ZTE;
        unsigned short* ZTw = ZT + (size_t)(hn & 1) * ZTE;
        const int grid = hasG ? 1280 : 384;
        if (h == 0)
            k_PVSZ1<0><<<grid, 256, 0, stream>>>(
                Pp, ZTr, bp, (float*)d_out, Gh, Gl, xh, xl,
                w_all + (long)hs * NB * NS, Sc, NTb + (long)hs * nwh,
                s_all + hs * ND, ZTw);
        else
            k_PVSZ1<1><<<grid, 256, 0, stream>>>(
                Pp, ZTr, bp, (float*)d_out, Gh, Gl, xh, xl,
                w_all + (long)hs * NB * NS, Sc, NTb + (long)hs * nwh,
                s_all + hs * ND, ZTw);
    }
}

// Round 14
// 1360.766 us; speedup vs baseline: 1.0965x; 1.0965x over previous
//
#include <hip/hip_runtime.h>

// ---------------------------------------------------------------------------
// MultiHeadAttention (full-width per-head projections), MI355X gfx950.
// Round 14: R12 revert (best verified, 1363us) + ONE change: k_su_b split by
// LDS class -> k_su_y (k_w+sh, 36KB, 4 blk/CU) + k_su_x (all MT+NT, 64KB,
// XCD-chunked). R13's persistence+distribution regressed (L3 pollution);
// reverted. All GEMM K-loops = replay-verified gemm_core64 verbatim.
// Math unchanged:
//   scores = softmax_t( 8*( x M_h x^T + w_t ) ),  M_h = Wq_h Wk_h^T
//   out    = sum_h P_h Z_h + bp,  Z_h = x N_h + bv_h Wp_h,  N_h = Wv_h Wp_h
// ---------------------------------------------------------------------------

typedef __attribute__((ext_vector_type(8))) short bf16x8;
typedef __attribute__((ext_vector_type(4))) float fx4;

#define NB 8
#define NS 1024
#define ND 768
#define NH 12

__device__ __forceinline__ unsigned short f2bf(float x) {
    unsigned int u = __float_as_uint(x);
    u += 0x7fffu + ((u >> 16) & 1u);   // round-to-nearest-even bf16
    return (unsigned short)(u >> 16);
}
__device__ __forceinline__ float bf2f(unsigned short h) {
    return __uint_as_float(((unsigned int)h) << 16);
}

// async global->LDS, 16B per lane; LDS base must be wave-uniform.
__device__ __forceinline__ void gll16(const void* g, void* l) {
    __builtin_amdgcn_global_load_lds(
        (const __attribute__((address_space(1))) void*)g,
        (__attribute__((address_space(3))) void*)l, 16, 0, 0);
}

// ---------------- elementwise body -------------------------------------------
__device__ __forceinline__ void split_body(const float* __restrict__ in,
                                           unsigned short* __restrict__ hi,
                                           unsigned short* __restrict__ lo, int i) {
    float4 v = ((const float4*)in)[i];
    ushort4 h, l;
    h.x = f2bf(v.x); l.x = f2bf(v.x - bf2f(h.x));
    h.y = f2bf(v.y); l.y = f2bf(v.y - bf2f(h.y));
    h.z = f2bf(v.z); l.z = f2bf(v.z - bf2f(h.z));
    h.w = f2bf(v.w); l.w = f2bf(v.w - bf2f(h.w));
    ((ushort4*)hi)[i] = h;
    ((ushort4*)lo)[i] = l;
}

// ---------------------------------------------------------------------------
// gemm_core64 — replay-verified (R9..R12): 128x128 tile, BK=64, 4 waves,
// single-buffer, per K-tile: sync -> stage (global_load_lds) -> sync -> ds+MFMA.
// LDS [128][64] bf16 tiles (16KB each). Swizzle pc = c_log ^ (row&7);
// staging source chunk (lane&7)^(lane>>3), linear LDS dest -> 0 conflicts.
// C/D layout (HW-verified): col = lane&15, row = (lane>>4)*4 + reg.
// ---------------------------------------------------------------------------
template<int NTERMS, class Epi>
__device__ __forceinline__ void gemm_core64(
    char* __restrict__ smem,
    const unsigned short* __restrict__ Ah, const unsigned short* __restrict__ Al, int lda,
    const unsigned short* __restrict__ Bh, const unsigned short* __restrict__ Bl, int ldb,
    int K, Epi epi)
{
    constexpr int TILE = 16384;              // bytes per [128][64] bf16 tile

    const int t = threadIdx.x;
    const int lane = t & 63;
    const int w = t >> 6;
    const int wm = (w >> 1) << 6;
    const int wn = (w & 1) << 6;
    const int lr = lane & 15;
    const int lg = lane >> 4;

    const int l3 = lane >> 3;
    const int cs = (lane & 7) ^ l3;
    const int ldsw = w << 12;                // wave-uniform LDS byte offset

    const long gsA = (long)(w * 32 + l3) * lda * 2 + cs * 16;
    const long gsB = (long)(w * 32 + l3) * ldb * 2 + cs * 16;
    const long giA = (long)lda * 16;         // +8 rows, in bytes
    const long giB = (long)ldb * 16;

    const char* pAh = (const char*)Ah;
    const char* pBh = (const char*)Bh;
    const char* pAl = (const char*)Al;
    const char* pBl = (const char*)Bl;
    char* smA  = smem;
    char* smB  = smem + TILE;
    char* smA2 = smem + ((NTERMS == 3) ? 2 * TILE : 0);
    char* smB2 = smem + ((NTERMS == 3) ? 3 * TILE : TILE);

    int rowA[4], rowB[4];
    #pragma unroll
    for (int i = 0; i < 4; i++) {
        rowA[i] = (wm + (i << 4) + lr) << 6;   // ushort index of row base
        rowB[i] = (wn + (i << 4) + lr) << 6;
    }
    const int lr7 = lr & 7;

    fx4 acc[4][4] = {};

    for (int k0 = 0; k0 < K; k0 += 64) {
        const long kb2 = (long)k0 * 2;
        __syncthreads();
        #pragma unroll
        for (int ii = 0; ii < 4; ii++) {
            const int lo = ldsw + (ii << 10);
            gll16(pAh + gsA + ii * giA + kb2, smA + lo);
            gll16(pBh + gsB + ii * giB + kb2, smB + lo);
            if constexpr (NTERMS == 3) {
                gll16(pAl + gsA + ii * giA + kb2, smA2 + lo);
                gll16(pBl + gsB + ii * giB + kb2, smB2 + lo);
            }
        }
        __syncthreads();

        #pragma unroll
        for (int kk = 0; kk < 2; kk++) {
            const int pc = (((kk << 2) + lg) ^ lr7) << 3;   // ushort offset
            bf16x8 fa[4], fb[4], fa2[4], fb2[4];
            #pragma unroll
            for (int i = 0; i < 4; i++) {
                fa[i] = *(const bf16x8*)((const unsigned short*)smA + rowA[i] + pc);
                fb[i] = *(const bf16x8*)((const unsigned short*)smB + rowB[i] + pc);
            }
            if constexpr (NTERMS == 3) {
                #pragma unroll
                for (int i = 0; i < 4; i++) {
                    fa2[i] = *(const bf16x8*)((const unsigned short*)smA2 + rowA[i] + pc);
                    fb2[i] = *(const bf16x8*)((const unsigned short*)smB2 + rowB[i] + pc);
                }
            }
            #pragma unroll
            for (int i = 0; i < 4; i++)
                #pragma unroll
                for (int j = 0; j < 4; j++) {
                    acc[i][j] = __builtin_amdgcn_mfma_f32_16x16x32_bf16(fa[i], fb[j], acc[i][j], 0, 0, 0);
                    if constexpr (NTERMS == 3) {
                        acc[i][j] = __builtin_amdgcn_mfma_f32_16x16x32_bf16(fa[i], fb2[j], acc[i][j], 0, 0, 0);
                        acc[i][j] = __builtin_amdgcn_mfma_f32_16x16x32_bf16(fa2[i], fb[j], acc[i][j], 0, 0, 0);
                    }
                }
        }
    }

    #pragma unroll
    for (int i = 0; i < 4; i++)
        #pragma unroll
        for (int j = 0; j < 4; j++)
            #pragma unroll
            for (int r = 0; r < 4; r++)
                epi(wm + (i << 4) + (lg << 2) + r, wn + (j << 4) + lr, acc[i][j][r]);
}

// ---------------- softmax body (wave per row) --------------------------------
__device__ __forceinline__ void softmax_row_core(const float* __restrict__ rp,
                                                 unsigned short* __restrict__ drow,
                                                 int lane) {
    const float4* src = (const float4*)rp + (lane << 2);
    float v[16];
    #pragma unroll
    for (int i = 0; i < 4; i++) {
        float4 a = src[i];
        v[i * 4 + 0] = a.x; v[i * 4 + 1] = a.y; v[i * 4 + 2] = a.z; v[i * 4 + 3] = a.w;
    }
    float m = v[0];
    #pragma unroll
    for (int i = 1; i < 16; i++) m = fmaxf(m, v[i]);
    #pragma unroll
    for (int o = 32; o > 0; o >>= 1) m = fmaxf(m, __shfl_xor(m, o));
    float s = 0.f, p[16];
    #pragma unroll
    for (int i = 0; i < 16; i++) { p[i] = __expf((v[i] - m) * 8.0f); s += p[i]; }
    #pragma unroll
    for (int o = 32; o > 0; o >>= 1) s += __shfl_xor(s, o);
    float inv = 1.0f / s;
    unsigned int wrd[8];
    #pragma unroll
    for (int i = 0; i < 8; i++) {
        unsigned int u0 = f2bf(p[2 * i] * inv);
        unsigned int u1 = f2bf(p[2 * i + 1] * inv);
        wrd[i] = u0 | (u1 << 16);
    }
    uint4* dst = (uint4*)(drow + (lane << 4));
    dst[0] = make_uint4(wrd[0], wrd[1], wrd[2], wrd[3]);
    dst[1] = make_uint4(wrd[4], wrd[5], wrd[6], wrd[7]);
}

// ------------------------- merged setup launch A (R12 verbatim) --------------
// [0,6144) x split | [6144,13056) Wq split | [13056,19968) Wk split |
// [19968,22272) rk | [22272,29184) Wv cast | [29184,30912) Wp transpose.
__global__ void k_su_a(
    const float* __restrict__ x, unsigned short* __restrict__ xh, unsigned short* __restrict__ xl,
    const float* __restrict__ Wq, unsigned short* __restrict__ Wqh, unsigned short* __restrict__ Wql,
    const float* __restrict__ Wk, unsigned short* __restrict__ Wkh, unsigned short* __restrict__ Wkl,
    const float* __restrict__ bq, float* __restrict__ rk,
    const float* __restrict__ Wv, unsigned short* __restrict__ Wvb,
    const float* __restrict__ Wp, unsigned short* __restrict__ WpT)
{
    __shared__ float tile[64][65];
    const int bx = blockIdx.x;
    if (bx < 6144) {
        split_body(x, xh, xl, bx * 256 + threadIdx.x);
    } else if (bx < 13056) {
        split_body(Wq, Wqh, Wql, (bx - 6144) * 256 + threadIdx.x);
    } else if (bx < 19968) {
        split_body(Wk, Wkh, Wkl, (bx - 13056) * 256 + threadIdx.x);
    } else if (bx < 22272) {
        const int idx = bx - 19968;            // [0,2304)
        const int h = idx / 192;
        const int d = (idx % 192) * 4 + ((int)threadIdx.x >> 6);
        const int lane = threadIdx.x & 63;
        const float4* row = (const float4*)(Wk + ((long)h * ND + d) * ND);
        const float4* bv4 = (const float4*)(bq + h * ND);
        float acc = 0.f;
        #pragma unroll
        for (int i = 0; i < 3; i++) {
            float4 a = row[lane + (i << 6)];
            float4 b = bv4[lane + (i << 6)];
            acc += a.x * b.x + a.y * b.y + a.z * b.z + a.w * b.w;
        }
        #pragma unroll
        for (int o = 32; o > 0; o >>= 1) acc += __shfl_xor(acc, o);
        if (lane == 0) rk[h * ND + d] = acc;
    } else if (bx < 29184) {
        int i = (bx - 22272) * 256 + threadIdx.x;
        float4 v = ((const float4*)Wv)[i];
        ushort4 h;
        h.x = f2bf(v.x); h.y = f2bf(v.y); h.z = f2bf(v.z); h.w = f2bf(v.w);
        ((ushort4*)Wvb)[i] = h;
    } else {
        const int idx = bx - 29184;            // [0,1728)
        const int c0 = (idx % 12) * 64;
        const int r0 = ((idx / 12) % 12) * 64;
        const long zo = (long)(idx / 144) * (ND * ND);
        const float* in = Wp + zo;
        unsigned short* oh = WpT + zo;
        const int tc = threadIdx.x & 63, t4 = threadIdx.x >> 6;
        #pragma unroll
        for (int i = 0; i < 16; i++) {
            int r = (i << 2) + t4;
            tile[r][tc] = in[(long)(r0 + r) * ND + c0 + tc];
        }
        __syncthreads();
        #pragma unroll
        for (int i = 0; i < 16; i++) {
            int c = (i << 2) + t4;
            oh[(long)(c0 + c) * ND + r0 + tc] = f2bf(tile[tc][c]);
        }
    }
}

// ------------------------- setup Y: k_w (2048) + sh (2304), 36KB LDS ---------
__global__ __launch_bounds__(256) void k_su_y(
    const float* __restrict__ x, const float* __restrict__ rk, float* __restrict__ w_all,
    const unsigned short* __restrict__ WpT, const float* __restrict__ bv,
    float* __restrict__ s_all)
{
    __shared__ float srk[NH * ND];   // 36KB
    const int bx = blockIdx.x;
    if (bx < 2048) {
        for (int i = threadIdx.x; i < NH * ND; i += 256) srk[i] = rk[i];
        __syncthreads();
        const int row = bx * 4 + ((int)threadIdx.x >> 6);
        const int lane = threadIdx.x & 63;
        const float4* xr = (const float4*)(x + (long)row * ND);
        float4 xa[3];
        #pragma unroll
        for (int i = 0; i < 3; i++) xa[i] = xr[lane + (i << 6)];
        for (int h = 0; h < NH; h++) {
            const float* r = srk + h * ND;
            float acc = 0.f;
            #pragma unroll
            for (int i = 0; i < 3; i++) {
                int e = (lane + (i << 6)) << 2;
                acc += xa[i].x * r[e] + xa[i].y * r[e + 1]
                     + xa[i].z * r[e + 2] + xa[i].w * r[e + 3];
            }
            #pragma unroll
            for (int o = 32; o > 0; o >>= 1) acc += __shfl_xor(acc, o);
            if (lane == 0) w_all[h * (NB * NS) + row] = acc;
        }
    } else {
        const int idx = bx - 2048;             // [0,2304)
        const int h = idx / 192;
        const int j = (idx % 192) * 4 + ((int)threadIdx.x >> 6);
        const int lane = threadIdx.x & 63;
        const ushort4* row = (const ushort4*)(WpT + ((long)h * ND + j) * ND);
        const float* bvh = bv + h * ND;
        float acc = 0.f;
        #pragma unroll
        for (int i = 0; i < 3; i++) {
            int c = lane + (i << 6);
            ushort4 u = row[c];
            int e = c << 2;
            acc += bf2f(u.x) * bvh[e] + bf2f(u.y) * bvh[e + 1]
                 + bf2f(u.z) * bvh[e + 2] + bf2f(u.w) * bvh[e + 3];
        }
        #pragma unroll
        for (int o = 32; o > 0; o >>= 1) acc += __shfl_xor(acc, o);
        if (lane == 0) s_all[h * ND + j] = acc;
    }
}

// ---------- setup X: all MT (432, XCD-chunked) + all NT (432) ---------------
__global__ __launch_bounds__(256, 2) void k_su_x(
    const unsigned short* __restrict__ Wkh, const unsigned short* __restrict__ Wkl,
    const unsigned short* __restrict__ Wqh, const unsigned short* __restrict__ Wql,
    unsigned short* __restrict__ MTh, unsigned short* __restrict__ MTl,
    const unsigned short* __restrict__ WpT, const unsigned short* __restrict__ Wvb,
    unsigned short* __restrict__ NTo)
{
    __shared__ __align__(16) char smem[65536];
    const int bx = blockIdx.x;
    if (bx < 432) {
        const int tid = (bx & 7) * 54 + (bx >> 3);   // XCD-contiguous tiles
        const int n0 = (tid % 6) << 7;
        const int m0 = ((tid / 6) % 6) << 7;
        const long hw = (long)(tid / 36) * (ND * ND);
        unsigned short* oh = MTh + hw + (long)m0 * ND + n0;
        unsigned short* ol = MTl + hw + (long)m0 * ND + n0;
        gemm_core64<3>(smem, Wkh + hw + (long)m0 * ND, Wkl + hw + (long)m0 * ND, ND,
                       Wqh + hw + (long)n0 * ND, Wql + hw + (long)n0 * ND, ND, ND,
                       [=](int r, int c, float v) {
                           unsigned short hh = f2bf(v);
                           oh[r * ND + c] = hh;
                           ol[r * ND + c] = f2bf(v - bf2f(hh));
                       });
    } else {
        const int b2 = bx - 432;
        const int tid = (b2 & 7) * 54 + (b2 >> 3);   // XCD-contiguous tiles
        const int n0 = (tid % 6) << 7;
        const int m0 = ((tid / 6) % 6) << 7;
        const long hw = (long)(tid / 36) * (ND * ND);
        unsigned short* o = NTo + hw + (long)m0 * ND + n0;
        gemm_core64<1>(smem, WpT + hw + (long)m0 * ND, nullptr, ND,
                       Wvb + hw + (long)n0 * ND, nullptr, ND, ND,
                       [=](int r, int c, float v) { o[r * ND + c] = f2bf(v); });
    }
}

// ------------------------- per-head kernels (R12 verbatim) -------------------

// G = x * M_h (split out), head-0 bootstrap. flat grid 384.
__global__ __launch_bounds__(256, 2) void k_G0(
    const unsigned short* __restrict__ xh, const unsigned short* __restrict__ xl,
    const unsigned short* __restrict__ MTh, const unsigned short* __restrict__ MTl,
    unsigned short* __restrict__ Gh, unsigned short* __restrict__ Gl)
{
    __shared__ __align__(16) char smem[65536];
    const int bx = blockIdx.x;
    const int xcd = bx & 7, idx = bx >> 3;
    const int m0 = (xcd * 8 + idx / 6) << 7;
    const int n0 = (idx % 6) << 7;
    unsigned short* oh = Gh + (long)m0 * ND + n0;
    unsigned short* ol = Gl + (long)m0 * ND + n0;
    gemm_core64<3>(smem, xh + (long)m0 * ND, xl + (long)m0 * ND, ND,
                   MTh + (long)n0 * ND, MTl + (long)n0 * ND, ND, ND,
                   [=](int r, int c, float v) {
                       unsigned short hh = f2bf(v);
                       oh[(long)r * ND + c] = hh;
                       ol[(long)r * ND + c] = f2bf(v - bf2f(hh));
                   });
}

// bootstrap: scores(0)+Z(0). grid 896.
__global__ __launch_bounds__(256, 2) void k_SZ(
    const unsigned short* __restrict__ Gh, const unsigned short* __restrict__ Gl,
    const unsigned short* __restrict__ xh, const unsigned short* __restrict__ xl,
    const float* __restrict__ wv, float* __restrict__ Sc,
    const unsigned short* __restrict__ NTh, const float* __restrict__ sh,
    unsigned short* __restrict__ ZT)
{
    __shared__ __align__(16) char smem[65536];
    const int bx = blockIdx.x;
    if (bx < 512) {
        const int bl = bx & 7, idx = bx >> 3;
        const int m0 = (idx >> 3) << 7;
        const int n0 = (idx & 7) << 7;
        const long ao = ((long)bl * NS + m0) * ND;
        const long bo = ((long)bl * NS + n0) * ND;
        const float* ww = wv + bl * NS + n0;
        float* out = Sc + ((long)bl * NS + m0) * NS + n0;
        gemm_core64<3>(smem, Gh + ao, Gl + ao, ND, xh + bo, xl + bo, ND, ND,
                       [=](int r, int c, float v) { out[(long)r * NS + c] = v + ww[c]; });
    } else {
        const int g = bx - 512;
        const int xcd = g & 7, idx = g >> 3;
        const int m0 = (xcd * 8 + idx / 6) << 7;
        const int n0 = (idx % 6) << 7;
        const int bl = m0 >> 10;
        const int s0 = m0 & (NS - 1);
        unsigned short* zt = ZT + (long)bl * (ND * NS);
        gemm_core64<1>(smem, xh + (long)m0 * ND, nullptr, ND,
                       NTh + (long)n0 * ND, nullptr, ND, ND,
                       [=](int r, int c, float v) {
                           zt[(long)(n0 + c) * NS + s0 + r] = f2bf(v + sh[n0 + c]);
                       });
    }
}

// blocks [0,2048): softmax Sc row -> packed Pp (stride NS); [2048,2432): G(h+1).
__global__ __launch_bounds__(256, 2) void k_SMG1(
    const float* __restrict__ Sc, unsigned short* __restrict__ Pp,
    const unsigned short* __restrict__ xh, const unsigned short* __restrict__ xl,
    const unsigned short* __restrict__ MTh, const unsigned short* __restrict__ MTl,
    unsigned short* __restrict__ Gh, unsigned short* __restrict__ Gl)
{
    __shared__ __align__(16) char smem[65536];
    const int bx = blockIdx.x;
    if (bx < 2048) {
        int row = bx * 4 + ((int)threadIdx.x >> 6);
        int lane = threadIdx.x & 63;
        softmax_row_core(Sc + (long)row * NS, Pp + (long)row * NS, lane);
    } else {
        const int g = bx - 2048;
        const int xcd = g & 7, idx = g >> 3;
        const int m0 = (xcd * 8 + idx / 6) << 7;
        const int n0 = (idx % 6) << 7;
        unsigned short* oh = Gh + (long)m0 * ND + n0;
        unsigned short* ol = Gl + (long)m0 * ND + n0;
        gemm_core64<3>(smem, xh + (long)m0 * ND, xl + (long)m0 * ND, ND,
                       MTh + (long)n0 * ND, MTl + (long)n0 * ND, ND, ND,
                       [=](int r, int c, float v) {
                           unsigned short hh = f2bf(v);
                           oh[(long)r * ND + c] = hh;
                           ol[(long)r * ND + c] = f2bf(v - bf2f(hh));
                       });
    }
}

// blocks [0,384): PV(h) = Pp . ZTr -> d_out (write/acc);
// [384,896): scores(h+1) -> Sc; [896,1280): Z(h+1) -> ZTw.
template<int MODE>   // 0: first head (write + bias), 1: accumulate
__global__ __launch_bounds__(256, 2) void k_PVSZ1(
    const unsigned short* __restrict__ Pp, const unsigned short* __restrict__ ZTr,
    const float* __restrict__ bp, float* __restrict__ outp,
    const unsigned short* __restrict__ Gh, const unsigned short* __restrict__ Gl,
    const unsigned short* __restrict__ xh, const unsigned short* __restrict__ xl,
    const float* __restrict__ wv, float* __restrict__ Sc,
    const unsigned short* __restrict__ NTh, const float* __restrict__ sh,
    unsigned short* __restrict__ ZTw)
{
    __shared__ __align__(16) char smem[65536];
    const int bx = blockIdx.x;
    if (bx < 384) {
        const int bl = bx & 7, idx = bx >> 3;
        const int m0 = (idx / 6) << 7;
        const int n0 = (idx % 6) << 7;
        const unsigned short* A = Pp + ((long)bl * NS + m0) * NS;
        const unsigned short* B = ZTr + (long)bl * (ND * NS) + (long)n0 * NS;
        float* o = outp + ((long)bl * NS + m0) * ND + n0;
        const float* bi = bp + n0;
        gemm_core64<1>(smem, A, nullptr, NS, B, nullptr, NS, NS,
                       [=](int r, int c, float v) {
                           float* d = o + (long)r * ND + c;
                           if constexpr (MODE == 0) *d = v + bi[c];
                           else *d += v;
                       });
    } else if (bx < 896) {
        const int b2 = bx - 384;
        const int bl = b2 & 7, idx = b2 >> 3;
        const int m0 = (idx >> 3) << 7;
        const int n0 = (idx & 7) << 7;
        const long ao = ((long)bl * NS + m0) * ND;
        const long bo = ((long)bl * NS + n0) * ND;
        const float* ww = wv + bl * NS + n0;
        float* out = Sc + ((long)bl * NS + m0) * NS + n0;
        gemm_core64<3>(smem, Gh + ao, Gl + ao, ND, xh + bo, xl + bo, ND, ND,
                       [=](int r, int c, float v) { out[(long)r * NS + c] = v + ww[c]; });
    } else {
        const int g = bx - 896;
        const int xcd = g & 7, idx = g >> 3;
        const int m0 = (xcd * 8 + idx / 6) << 7;
        const int n0 = (idx % 6) << 7;
        const int bl = m0 >> 10;
        const int s0 = m0 & (NS - 1);
        unsigned short* zt = ZTw + (long)bl * (ND * NS);
        gemm_core64<1>(smem, xh + (long)m0 * ND, nullptr, ND,
                       NTh + (long)n0 * ND, nullptr, ND, ND,
                       [=](int r, int c, float v) {
                           zt[(long)(n0 + c) * NS + s0 + r] = f2bf(v + sh[n0 + c]);
                       });
    }
}

// ---------------------------------------------------------------------------

extern "C" void kernel_launch(void* const* d_in, const int* in_sizes, int n_in,
                              void* d_out, int out_size, void* d_ws, size_t ws_size,
                              hipStream_t stream) {
    (void)in_sizes; (void)n_in; (void)out_size; (void)ws_size;
    const float* x  = (const float*)d_in[0];
    const float* Wq = (const float*)d_in[1];
    const float* bq = (const float*)d_in[2];
    const float* Wk = (const float*)d_in[3];
    const float* bk = (const float*)d_in[4];  (void)bk;  // cancels in softmax
    const float* Wv = (const float*)d_in[5];
    const float* bv = (const float*)d_in[6];
    const float* Wp = (const float*)d_in[7];
    const float* bp = (const float*)d_in[8];

    const size_t nx  = (size_t)NB * NS * ND;   // 6,291,456
    const size_t nw  = (size_t)NH * ND * ND;   // 7,077,888
    const size_t nwh = (size_t)ND * ND;
    const size_t PPE = (size_t)NB * NS * NS;   // 8,388,608
    const size_t ZTE = (size_t)NB * NS * ND;

    char* p = (char*)d_ws;
    auto alloc = [&](size_t bytes) -> void* {
        void* r = (void*)p;
        p += (bytes + 255) & ~(size_t)255;
        return r;
    };
    // persistent (~110.6 MB)
    unsigned short* xh   = (unsigned short*)alloc(nx * 2);
    unsigned short* xl   = (unsigned short*)alloc(nx * 2);
    unsigned short* MTh  = (unsigned short*)alloc(nw * 2);
    unsigned short* MTl  = (unsigned short*)alloc(nw * 2);
    unsigned short* NTb  = (unsigned short*)alloc(nw * 2);
    float*          rk   = (float*)alloc((size_t)NH * ND * 4);
    float*          s_all= (float*)alloc((size_t)NH * ND * 4);
    float*          w_all= (float*)alloc((size_t)NH * NB * NS * 4);
    // phase-B arena (~125.8 MB): Sc, G, Pp, 2x ZT  (total ws ~236 MB)
    float*          Sc = (float*)alloc(PPE * 4);
    unsigned short* Gh = (unsigned short*)alloc(nx * 2);
    unsigned short* Gl = (unsigned short*)alloc(nx * 2);
    unsigned short* Pp = (unsigned short*)alloc(PPE * 2);
    unsigned short* ZT = (unsigned short*)alloc(2 * ZTE * 2);
    // setup overlays inside the phase-B arena (dead until G0/SZ):
    // splits at Sc [0,56.6MB); Wvb/WpT at [56.6,84.9MB)
    unsigned short* Wqh = (unsigned short*)Sc;
    unsigned short* Wql = Wqh + nw;
    unsigned short* Wkh = Wql + nw;
    unsigned short* Wkl = Wkh + nw;
    unsigned short* Wvb = Wkl + nw;
    unsigned short* WpT = Wvb + nw;

    // ---------------- setup (3 fused launches) ----------------
    k_su_a<<<30912, 256, 0, stream>>>(x, xh, xl, Wq, Wqh, Wql, Wk, Wkh, Wkl,
                                      bq, rk, Wv, Wvb, Wp, WpT);
    k_su_y<<<4352, 256, 0, stream>>>(x, rk, w_all, WpT, bv, s_all);
    k_su_x<<<864, 256, 0, stream>>>(Wkh, Wkl, Wqh, Wql, MTh, MTl, WpT, Wvb, NTb);

    // ---------------- per-head pipeline (2 launches/head) ----------------
    k_G0<<<384, 256, 0, stream>>>(xh, xl, MTh, MTl, Gh, Gl);
    k_SZ<<<896, 256, 0, stream>>>(Gh, Gl, xh, xl, w_all, Sc, NTb, s_all, ZT);
    for (int h = 0; h < NH; h++) {
        const int hn = h + 1;
        const bool hasG = hn < NH;
        const int hs = hasG ? hn : 0;
        k_SMG1<<<hasG ? 2432 : 2048, 256, 0, stream>>>(
            Sc, Pp, xh, xl, MTh + (long)hs * nwh, MTl + (long)hs * nwh, Gh, Gl);
        unsigned short* ZTr = ZT + (size_t)(h & 1) * ZTE;
        unsigned short* ZTw = ZT + (size_t)(hn & 1) * ZTE;
        const int grid = hasG ? 1280 : 384;
        if (h == 0)
            k_PVSZ1<0><<<grid, 256, 0, stream>>>(
                Pp, ZTr, bp, (float*)d_out, Gh, Gl, xh, xl,
                w_all + (long)hs * NB * NS, Sc, NTb + (long)hs * nwh,
                s_all + hs * ND, ZTw);
        else
            k_PVSZ1<1><<<grid, 256, 0, stream>>>(
                Pp, ZTr, bp, (float*)d_out, Gh, Gl, xh, xl,
                w_all + (long)hs * NB * NS, Sc, NTb + (long)hs * nwh,
                s_all + hs * ND, ZTw);
    }
}